// Round 16
// baseline (457.787 us; speedup 1.0000x reference)
//
#include <hip/hip_runtime.h>
#include <stdint.h>

typedef __attribute__((ext_vector_type(4))) float f32x4;
typedef __attribute__((ext_vector_type(8))) short short8;

#define HEADS 16
#define TT 2048

__device__ __forceinline__ float b2f(unsigned short u) {
  return __builtin_bit_cast(float, (uint32_t)u << 16);
}
__device__ __forceinline__ unsigned short f2bf(float f) {
  uint32_t u = __builtin_bit_cast(uint32_t, f);
  u += 0x7fffu + ((u >> 16) & 1u);
  return (unsigned short)(u >> 16);
}
__device__ __forceinline__ uint32_t pk2(float a, float b) {
  return (uint32_t)f2bf(a) | ((uint32_t)f2bf(b) << 16);
}
// asm-laundered zero DEPENDENT on x: serializes probe reps
__device__ __forceinline__ int lzero(float x) {
  int d;
  asm volatile("v_and_b32 %0, 0, %1" : "=v"(d) : "v"(__builtin_bit_cast(int, x)));
  return d;
}

// p[h][i] = sum_d Wk[i,h,d] * q[h,d]   (fold q into kv K-half; fp32)
__global__ void prep_p(const float* __restrict__ kv, const float* __restrict__ q,
                       float* __restrict__ p) {
  int idx = blockIdx.x * 256 + threadIdx.x;       // 16384 = 16*1024
  int h = idx >> 10, i = idx & 1023;
  const float* kvp = kv + (size_t)i * 2048 + (size_t)h * 128;
  const float* qp = q + h * 64;
  float s = 0.f;
#pragma unroll 8
  for (int d = 0; d < 64; ++d) s += kvp[2 * d] * qp[d];
  p[idx] = s;
}

// wv[hd][i] = bf16(kv[i*2048 + 2*hd + 1]) — LDS-tiled transpose
__global__ __launch_bounds__(256) void prep_wv(const float* __restrict__ kv,
                                               unsigned short* __restrict__ wv) {
  __shared__ unsigned short tile[64][66];
  int hd0 = blockIdx.x * 64, i0 = blockIdx.y * 64;
  int tid = threadIdx.x;
  int jj = tid & 63, r4 = tid >> 6;
#pragma unroll
  for (int s = 0; s < 16; ++s) {
    int ii = s * 4 + r4;
    tile[ii][jj] = f2bf(kv[(size_t)(i0 + ii) * 2048 + 2 * (hd0 + jj) + 1]);
  }
  __syncthreads();
#pragma unroll
  for (int s = 0; s < 16; ++s) {
    int jj2 = s * 4 + r4, ii2 = tid & 63;
    wv[(size_t)(hd0 + jj2) * 1024 + i0 + ii2] = tile[ii2][jj2];
  }
}

// st[b][h][t] = sum_i x[b,t,i]*p[h,i] (fp32) AND xb = bf16(x) — x read ONCE
__global__ __launch_bounds__(256) void stx_kernel(const float* __restrict__ x,
                                                  const float* __restrict__ p,
                                                  unsigned short* __restrict__ xb,
                                                  float* __restrict__ st) {
  __shared__ float xs[32][129];
  __shared__ float ps[16][129];
  int tid = threadIdx.x;
  int t0 = blockIdx.x * 32;
  int tt = tid & 31, hb = tid >> 5;               // 32 tokens x 8 head-pairs
  float a0 = 0.f, a1 = 0.f;
  for (int kc = 0; kc < 1024; kc += 128) {
    __syncthreads();
#pragma unroll
    for (int vv = 0; vv < 4; ++vv) {              // x: 32 rows x 128 f32
      int idx = tid + vv * 256;
      int row = idx >> 5, c4 = idx & 31;
      float4 val = *(const float4*)&x[(size_t)(t0 + row) * 1024 + kc + c4 * 4];
      float* dst = &xs[row][c4 * 4];
      dst[0] = val.x; dst[1] = val.y; dst[2] = val.z; dst[3] = val.w;
      *(uint2*)&xb[(size_t)(t0 + row) * 1024 + kc + c4 * 4] =
          uint2{pk2(val.x, val.y), pk2(val.z, val.w)};
    }
#pragma unroll
    for (int vv = 0; vv < 2; ++vv) {              // p: 16 rows x 128 f32
      int idx = tid + vv * 256;
      int row = idx >> 5, c4 = idx & 31;
      float4 val = *(const float4*)&p[(size_t)row * 1024 + kc + c4 * 4];
      float* dst = &ps[row][c4 * 4];
      dst[0] = val.x; dst[1] = val.y; dst[2] = val.z; dst[3] = val.w;
    }
    __syncthreads();
#pragma unroll 4
    for (int kk = 0; kk < 128; ++kk) {
      float xv = xs[tt][kk];
      a0 += xv * ps[hb * 2 + 0][kk];
      a1 += xv * ps[hb * 2 + 1][kk];
    }
  }
  int tg = t0 + tt, b = tg >> 11, tl = tg & 2047;
  st[(size_t)(b * HEADS + hb * 2 + 0) * TT + tl] = a0;
  st[(size_t)(b * HEADS + hb * 2 + 1) * TT + tl] = a1;
}

// V = xb @ Wv — MFMA 128x128 tile, K=1024, global_load_lds width=16 staging
__global__ __launch_bounds__(256) void vgemm(const unsigned short* __restrict__ A,
                                             const unsigned short* __restrict__ Bt,
                                             unsigned short* __restrict__ V) {
  __shared__ unsigned short As[128 * 32];         // 8 KB, linear
  __shared__ unsigned short Bs[128 * 32];         // 8 KB, linear
  int tid = threadIdx.x;
  int wave = tid >> 6, lane = tid & 63;
  int m0 = blockIdx.y * 128, n0 = blockIdx.x * 128;
  int wr = wave >> 1, wc = wave & 1;
  int lx = lane & 15, lq = lane >> 4;
  int srow = (wave << 4) + (lane >> 2);           // + c*64
  int scol = (lane & 3) << 3;
  unsigned short* AsW = As + (wave << 9);
  unsigned short* BsW = Bs + (wave << 9);
  f32x4 acc[4][4] = {};
  for (int kt = 0; kt < 1024; kt += 32) {
    __syncthreads();
#pragma unroll
    for (int c = 0; c < 2; ++c) {
      __builtin_amdgcn_global_load_lds(
          (const uint32_t*)&A[(size_t)(m0 + c * 64 + srow) * 1024 + kt + scol],
          (uint32_t*)(AsW + c * 2048), 16, 0, 0);
      __builtin_amdgcn_global_load_lds(
          (const uint32_t*)&Bt[(size_t)(n0 + c * 64 + srow) * 1024 + kt + scol],
          (uint32_t*)(BsW + c * 2048), 16, 0, 0);
    }
    __syncthreads();
    short8 af[4], bfr[4];
#pragma unroll
    for (int i = 0; i < 4; ++i)
      af[i] = *(const short8*)&As[(wr * 64 + i * 16 + lx) * 32 + lq * 8];
#pragma unroll
    for (int j = 0; j < 4; ++j)
      bfr[j] = *(const short8*)&Bs[(wc * 64 + j * 16 + lx) * 32 + lq * 8];
#pragma unroll
    for (int i = 0; i < 4; ++i)
#pragma unroll
      for (int j = 0; j < 4; ++j)
        acc[i][j] = __builtin_amdgcn_mfma_f32_16x16x32_bf16(af[i], bfr[j], acc[i][j], 0, 0, 0);
  }
#pragma unroll
  for (int i = 0; i < 4; ++i)
#pragma unroll
    for (int j = 0; j < 4; ++j)
#pragma unroll
      for (int r = 0; r < 4; ++r) {
        int m = m0 + wr * 64 + i * 16 + lq * 4 + r;
        int n = n0 + wc * 64 + j * 16 + lx;
        int b = m >> 11, tl = m & 2047, h = n >> 6, d = n & 63;
        V[((size_t)(b * HEADS + h) << 17) + (tl << 6) + d] = f2bf(acc[i][j][r]);
      }
}

// Phase 1: per-chunk (32 tok) max, exp-sum, weighted v-sums; loads hoisted
__global__ __launch_bounds__(64) void scan1(const float* __restrict__ st,
                                            const unsigned short* __restrict__ v,
                                            float* __restrict__ cmax,
                                            float* __restrict__ csum,
                                            float* __restrict__ cw) {
  int blk = blockIdx.x;                           // bh*64 + c
  int bh = blk >> 6, c = blk & 63;
  int lane = threadIdx.x;
  int t0 = c * 32;
  const float* stp = st + (size_t)bh * TT + t0;
  const unsigned short* vp = v + ((size_t)bh << 17) + ((size_t)t0 << 6);
  float vj[32];
#pragma unroll
  for (int j = 0; j < 32; ++j) vj[j] = b2f(vp[j * 64 + lane]);  // batched
  float stv = (lane < 32) ? stp[lane] : -1e30f;
  float Mc = stv;
#pragma unroll
  for (int off = 32; off; off >>= 1) Mc = fmaxf(Mc, __shfl_xor(Mc, off));
  float el = (lane < 32) ? __expf(stv - Mc) : 0.f;
  float S = el;
#pragma unroll
  for (int off = 32; off; off >>= 1) S += __shfl_xor(S, off);
  float W = 0.f;
#pragma unroll
  for (int j = 0; j < 32; ++j) W = fmaf(__shfl(el, j), vj[j], W);
  if (lane == 0) { cmax[blk] = Mc; csum[blk] = S; }
  cw[(size_t)blk * 64 + lane] = W;
}

// Phase 2: wave-parallel prefix over 64 chunks (lane = chunk). Exclusive via
// SHIFT of inclusive (subtraction-free — partial sums only involve chunks < c).
__global__ __launch_bounds__(1024) void scan2(const float* __restrict__ cmax,
                                              const float* __restrict__ csum,
                                              const float* __restrict__ cw,
                                              float* __restrict__ Mg,
                                              float* __restrict__ E0,
                                              float* __restrict__ W0) {
  int bh = blockIdx.x;
  int tid = threadIdx.x, wave = tid >> 6, lane = tid & 63;   // lane = chunk
  float cm = cmax[bh * 64 + lane];
  float M = cm;
#pragma unroll
  for (int off = 32; off; off >>= 1) M = fmaxf(M, __shfl_xor(M, off));
  float f = __expf(cm - M);
  if (wave == 0) {
    if (lane == 0) Mg[bh] = M;
    float incl = csum[bh * 64 + lane] * f;
#pragma unroll
    for (int off = 1; off < 64; off <<= 1) {
      float n = __shfl_up(incl, off);
      if (lane >= off) incl += n;
    }
    float excl = __shfl_up(incl, 1);              // shift, not subtract
    E0[bh * 64 + lane] = (lane == 0) ? 0.f : excl;
  }
#pragma unroll
  for (int dd = 0; dd < 4; ++dd) {
    int d = wave * 4 + dd;
    float incl = cw[((size_t)bh * 64 + lane) * 64 + d] * f;
#pragma unroll
    for (int off = 1; off < 64; off <<= 1) {
      float n = __shfl_up(incl, off);
      if (lane >= off) incl += n;
    }
    float excl = __shfl_up(incl, 1);              // shift, not subtract
    W0[((size_t)bh * 64 + lane) * 64 + d] = (lane == 0) ? 0.f : excl;
  }
}

// Phase 3: ATOMIC-FREE (r14: 48->~7µs confirmed).
__global__ __launch_bounds__(1024, 4) void scan3(const float* __restrict__ st,
                                                 const unsigned short* __restrict__ v,
                                                 const float* __restrict__ Mg,
                                                 const float* __restrict__ E0,
                                                 const float* __restrict__ W0,
                                                 float* __restrict__ h) {
  __shared__ float hq[16][16][64];                // 64 KB: [head][tok-half][dim]
  int tid = threadIdx.x;
  int wave = tid >> 6, lane = tid & 63;
  int c = blockIdx.x, b = blockIdx.y;
  int bh = b * HEADS + wave;
  int t0 = c * 32;
  const float* stp = st + (size_t)bh * TT + t0;
  const unsigned short* vp = v + ((size_t)bh << 17) + ((size_t)t0 << 6);
#define LOADV(J) float vj##J = b2f(vp[(J) * 64 + lane]);
  LOADV(0)  LOADV(1)  LOADV(2)  LOADV(3)  LOADV(4)  LOADV(5)  LOADV(6)  LOADV(7)
  LOADV(8)  LOADV(9)  LOADV(10) LOADV(11) LOADV(12) LOADV(13) LOADV(14) LOADV(15)
  LOADV(16) LOADV(17) LOADV(18) LOADV(19) LOADV(20) LOADV(21) LOADV(22) LOADV(23)
  LOADV(24) LOADV(25) LOADV(26) LOADV(27) LOADV(28) LOADV(29) LOADV(30) LOADV(31)
#undef LOADV
  float M = Mg[bh];
  float runU = E0[bh * 64 + c];
  float runW = W0[(size_t)(bh * 64 + c) * 64 + lane];
  float el = (lane < 32) ? __expf(stp[lane] - M) : 0.f;
#define STEP(J, JJ) { \
    float ej = __shfl(el, J); \
    runU += ej; \
    runW = fmaf(ej, vj##J, runW); \
    hq[wave][JJ][lane] = runW * __builtin_amdgcn_rcpf(fmaxf(runU, 1e-30f)) * 0.0625f; }
  STEP(0,0)   STEP(1,1)   STEP(2,2)   STEP(3,3)
  STEP(4,4)   STEP(5,5)   STEP(6,6)   STEP(7,7)
  STEP(8,8)   STEP(9,9)   STEP(10,10) STEP(11,11)
  STEP(12,12) STEP(13,13) STEP(14,14) STEP(15,15)
  __syncthreads();
  {                                               // wave = token, lane = dim
    float s = 0.f;
#pragma unroll
    for (int h2 = 0; h2 < 16; ++h2) s += hq[h2][wave][lane];
    h[((size_t)(b * TT + t0 + wave) << 6) + lane] = s;
  }
  __syncthreads();                                // hq reusable
  STEP(16,0)  STEP(17,1)  STEP(18,2)  STEP(19,3)
  STEP(20,4)  STEP(21,5)  STEP(22,6)  STEP(23,7)
  STEP(24,8)  STEP(25,9)  STEP(26,10) STEP(27,11)
  STEP(28,12) STEP(29,13) STEP(30,14) STEP(31,15)
#undef STEP
  __syncthreads();
  {
    float s = 0.f;
#pragma unroll
    for (int h2 = 0; h2 < 16; ++h2) s += hq[h2][wave][lane];
    h[((size_t)(b * TT + t0 + 16 + wave) << 6) + lane] = s;
  }
}

// out = h @ out_w^T + out_b  (fp32 -> bf16 staging; fp32 out, bias fused)
__global__ __launch_bounds__(256) void fgemm(const float* __restrict__ Ah,
                                             const float* __restrict__ Bw,
                                             const float* __restrict__ bias,
                                             float* __restrict__ C) {
  __shared__ unsigned short As[128 * 40];
  __shared__ unsigned short Bs[128 * 40];
  int tid = threadIdx.x;
  int wave = tid >> 6, lane = tid & 63;
  int m0 = blockIdx.y * 128, n0 = blockIdx.x * 128;
  int wr = wave >> 1, wc = wave & 1;
  int lx = lane & 15, lq = lane >> 4;
  f32x4 acc[4][4] = {};
  for (int kt = 0; kt < 64; kt += 32) {
    __syncthreads();
#pragma unroll
    for (int vv = 0; vv < 4; ++vv) {
      int c = tid + vv * 256;
      int r = (c & 511) >> 2, seg = c & 3;
      if (c < 512) {
        float4 a = *(const float4*)&Ah[(size_t)(m0 + r) * 64 + kt + seg * 8];
        float4 a2 = *(const float4*)&Ah[(size_t)(m0 + r) * 64 + kt + seg * 8 + 4];
        *(uint4*)&As[r * 40 + seg * 8] =
            uint4{pk2(a.x, a.y), pk2(a.z, a.w), pk2(a2.x, a2.y), pk2(a2.z, a2.w)};
      } else {
        float4 bq = *(const float4*)&Bw[(size_t)(n0 + r) * 64 + kt + seg * 8];
        float4 b2 = *(const float4*)&Bw[(size_t)(n0 + r) * 64 + kt + seg * 8 + 4];
        *(uint4*)&Bs[r * 40 + seg * 8] =
            uint4{pk2(bq.x, bq.y), pk2(bq.z, bq.w), pk2(b2.x, b2.y), pk2(b2.z, b2.w)};
      }
    }
    __syncthreads();
    short8 af[4], bfr[4];
#pragma unroll
    for (int i = 0; i < 4; ++i)
      af[i] = *(const short8*)&As[(wr * 64 + i * 16 + lx) * 40 + lq * 8];
#pragma unroll
    for (int j = 0; j < 4; ++j)
      bfr[j] = *(const short8*)&Bs[(wc * 64 + j * 16 + lx) * 40 + lq * 8];
#pragma unroll
    for (int i = 0; i < 4; ++i)
#pragma unroll
      for (int j = 0; j < 4; ++j)
        acc[i][j] = __builtin_amdgcn_mfma_f32_16x16x32_bf16(af[i], bfr[j], acc[i][j], 0, 0, 0);
  }
#pragma unroll
  for (int i = 0; i < 4; ++i)
#pragma unroll
    for (int j = 0; j < 4; ++j)
#pragma unroll
      for (int r = 0; r < 4; ++r) {
        int m = m0 + wr * 64 + i * 16 + lq * 4 + r;
        int n = n0 + wc * 64 + j * 16 + lx;
        C[(size_t)m * 1024 + n] = acc[i][j][r] + bias[n];
      }
}

// ============== ATTRIBUTION PROBES (this round only; removed next) ==========
// Amplified copies of the 4 unknown-cost kernels, run AFTER fgemm; write only
// buffers dead after their consumers (xb/st/V/cmax/csum/cw + ws[0..32MB]).
// probe/reps = true kernel cost; invisible (<42µs fills) => cost < 42/reps.

__global__ __launch_bounds__(256) void probe_stx(const float* __restrict__ x,
                                                 const float* __restrict__ p,
                                                 unsigned short* __restrict__ xb,
                                                 float* __restrict__ st) {
  __shared__ float xs[32][129];
  __shared__ float ps[16][129];
  int tid = threadIdx.x;
  int t0 = blockIdx.x * 32;
  int tt = tid & 31, hb = tid >> 5;
  for (int r = 0; r < 4; ++r) {                   // x4
    float a0 = 0.f, a1 = 0.f;
    for (int kc = 0; kc < 1024; kc += 128) {
      __syncthreads();
#pragma unroll
      for (int vv = 0; vv < 4; ++vv) {
        int idx = tid + vv * 256;
        int row = idx >> 5, c4 = idx & 31;
        float4 val = *(const float4*)&x[(size_t)(t0 + row) * 1024 + kc + c4 * 4];
        float* dst = &xs[row][c4 * 4];
        dst[0] = val.x; dst[1] = val.y; dst[2] = val.z; dst[3] = val.w;
        *(uint2*)&xb[(size_t)(t0 + row) * 1024 + kc + c4 * 4] =
            uint2{pk2(val.x, val.y), pk2(val.z, val.w)};
      }
#pragma unroll
      for (int vv = 0; vv < 2; ++vv) {
        int idx = tid + vv * 256;
        int row = idx >> 5, c4 = idx & 31;
        float4 val = *(const float4*)&p[(size_t)row * 1024 + kc + c4 * 4];
        float* dst = &ps[row][c4 * 4];
        dst[0] = val.x; dst[1] = val.y; dst[2] = val.z; dst[3] = val.w;
      }
      __syncthreads();
#pragma unroll 4
      for (int kk = 0; kk < 128; ++kk) {
        float xv = xs[tt][kk];
        a0 += xv * ps[hb * 2 + 0][kk];
        a1 += xv * ps[hb * 2 + 1][kk];
      }
    }
    int tg = t0 + tt, b = tg >> 11, tl = tg & 2047;
    st[(size_t)(b * HEADS + hb * 2 + 0) * TT + tl] = a0;
    st[(size_t)(b * HEADS + hb * 2 + 1) * TT + tl] = a1;
    __syncthreads();
  }
}

__global__ __launch_bounds__(256) void probe_vgemm(const unsigned short* __restrict__ A,
                                                   const unsigned short* __restrict__ Bt,
                                                   unsigned short* __restrict__ V) {
  __shared__ unsigned short As[128 * 32];
  __shared__ unsigned short Bs[128 * 32];
  int tid = threadIdx.x;
  int wave = tid >> 6, lane = tid & 63;
  int m0 = blockIdx.y * 128, n0 = blockIdx.x * 128;
  int wr = wave >> 1, wc = wave & 1;
  int lx = lane & 15, lq = lane >> 4;
  int srow = (wave << 4) + (lane >> 2);
  int scol = (lane & 3) << 3;
  unsigned short* AsW = As + (wave << 9);
  unsigned short* BsW = Bs + (wave << 9);
  f32x4 acc[4][4] = {};
  for (int r = 0; r < 4; ++r)                     // x4 K-loop
    for (int kt = 0; kt < 1024; kt += 32) {
      __syncthreads();
#pragma unroll
      for (int c = 0; c < 2; ++c) {
        __builtin_amdgcn_global_load_lds(
            (const uint32_t*)&A[(size_t)(m0 + c * 64 + srow) * 1024 + kt + scol],
            (uint32_t*)(AsW + c * 2048), 16, 0, 0);
        __builtin_amdgcn_global_load_lds(
            (const uint32_t*)&Bt[(size_t)(n0 + c * 64 + srow) * 1024 + kt + scol],
            (uint32_t*)(BsW + c * 2048), 16, 0, 0);
      }
      __syncthreads();
      short8 af[4], bfr[4];
#pragma unroll
      for (int i = 0; i < 4; ++i)
        af[i] = *(const short8*)&As[(wr * 64 + i * 16 + lx) * 32 + lq * 8];
#pragma unroll
      for (int j = 0; j < 4; ++j)
        bfr[j] = *(const short8*)&Bs[(wc * 64 + j * 16 + lx) * 32 + lq * 8];
#pragma unroll
      for (int i = 0; i < 4; ++i)
#pragma unroll
        for (int j = 0; j < 4; ++j)
          acc[i][j] = __builtin_amdgcn_mfma_f32_16x16x32_bf16(af[i], bfr[j], acc[i][j], 0, 0, 0);
    }
#pragma unroll
  for (int i = 0; i < 4; ++i)
#pragma unroll
    for (int j = 0; j < 4; ++j)
#pragma unroll
      for (int r = 0; r < 4; ++r) {
        int m = m0 + wr * 64 + i * 16 + lq * 4 + r;
        int n = n0 + wc * 64 + j * 16 + lx;
        int b = m >> 11, tl = m & 2047, h = n >> 6, d = n & 63;
        V[((size_t)(b * HEADS + h) << 17) + (tl << 6) + d] = f2bf(acc[i][j][r]);
      }
}

__global__ __launch_bounds__(64) void probe_scan1(const float* __restrict__ st,
                                                  const unsigned short* __restrict__ v,
                                                  float* __restrict__ cmax,
                                                  float* __restrict__ csum,
                                                  float* __restrict__ cw) {
  int blk = blockIdx.x;
  int bh = blk >> 6, c = blk & 63;
  int lane = threadIdx.x;
  int t0 = c * 32;
  float W = 0.f;
  for (int r = 0; r < 8; ++r) {                   // x8, lzero-chained
    const float* stp = st + (size_t)bh * TT + t0 + lzero(W);
    const unsigned short* vp = v + ((size_t)bh << 17) + ((size_t)t0 << 6) + lzero(W);
    float vj[32];
#pragma unroll
    for (int j = 0; j < 32; ++j) vj[j] = b2f(vp[j * 64 + lane]);
    float stv = (lane < 32) ? stp[lane] : -1e30f;
    float Mc = stv;
#pragma unroll
    for (int off = 32; off; off >>= 1) Mc = fmaxf(Mc, __shfl_xor(Mc, off));
    float el = (lane < 32) ? __expf(stv - Mc) : 0.f;
    float S = el;
#pragma unroll
    for (int off = 32; off; off >>= 1) S += __shfl_xor(S, off);
    W = 0.f;
#pragma unroll
    for (int j = 0; j < 32; ++j) W = fmaf(__shfl(el, j), vj[j], W);
    if (lane == 0) { cmax[blk] = Mc; csum[blk] = S; }
    cw[(size_t)blk * 64 + lane] = W;
  }
}

__global__ __launch_bounds__(256) void probe_fgemm(const float* __restrict__ Ah,
                                                   const float* __restrict__ Bw,
                                                   const float* __restrict__ bias,
                                                   float* __restrict__ C) {
  __shared__ unsigned short As[128 * 40];
  __shared__ unsigned short Bs[128 * 40];
  int tid = threadIdx.x;
  int wave = tid >> 6, lane = tid & 63;
  int m0 = blockIdx.y * 128, n0 = blockIdx.x * 128;
  int wr = wave >> 1, wc = wave & 1;
  int lx = lane & 15, lq = lane >> 4;
  for (int rr = 0; rr < 8; ++rr) {                // x8 whole body
    f32x4 acc[4][4] = {};
    for (int kt = 0; kt < 64; kt += 32) {
      __syncthreads();
#pragma unroll
      for (int vv = 0; vv < 4; ++vv) {
        int c = tid + vv * 256;
        int r = (c & 511) >> 2, seg = c & 3;
        if (c < 512) {
          float4 a = *(const float4*)&Ah[(size_t)(m0 + r) * 64 + kt + seg * 8];
          float4 a2 = *(const float4*)&Ah[(size_t)(m0 + r) * 64 + kt + seg * 8 + 4];
          *(uint4*)&As[r * 40 + seg * 8] =
              uint4{pk2(a.x, a.y), pk2(a.z, a.w), pk2(a2.x, a2.y), pk2(a2.z, a2.w)};
        } else {
          float4 bq = *(const float4*)&Bw[(size_t)(n0 + r) * 64 + kt + seg * 8];
          float4 b2 = *(const float4*)&Bw[(size_t)(n0 + r) * 64 + kt + seg * 8 + 4];
          *(uint4*)&Bs[r * 40 + seg * 8] =
              uint4{pk2(bq.x, bq.y), pk2(bq.z, bq.w), pk2(b2.x, b2.y), pk2(b2.z, b2.w)};
        }
      }
      __syncthreads();
      short8 af[4], bfr[4];
#pragma unroll
      for (int i = 0; i < 4; ++i)
        af[i] = *(const short8*)&As[(wr * 64 + i * 16 + lx) * 40 + lq * 8];
#pragma unroll
      for (int j = 0; j < 4; ++j)
        bfr[j] = *(const short8*)&Bs[(wc * 64 + j * 16 + lx) * 40 + lq * 8];
#pragma unroll
      for (int i = 0; i < 4; ++i)
#pragma unroll
        for (int j = 0; j < 4; ++j)
          acc[i][j] = __builtin_amdgcn_mfma_f32_16x16x32_bf16(af[i], bfr[j], acc[i][j], 0, 0, 0);
    }
#pragma unroll
    for (int i = 0; i < 4; ++i)
#pragma unroll
      for (int j = 0; j < 4; ++j)
#pragma unroll
        for (int r = 0; r < 4; ++r) {
          int m = m0 + wr * 64 + i * 16 + lq * 4 + r;
          int n = n0 + wc * 64 + j * 16 + lx;
          C[(size_t)m * 1024 + n] = acc[i][j][r] + bias[n];
        }
    __syncthreads();
  }
}
// ============================================================================

extern "C" void kernel_launch(void* const* d_in, const int* in_sizes, int n_in,
                              void* d_out, int out_size, void* d_ws, size_t ws_size,
                              hipStream_t stream) {
  (void)in_sizes; (void)n_in; (void)out_size; (void)ws_size;
  const float* x  = (const float*)d_in[0];
  const float* kv = (const float*)d_in[1];
  const float* q  = (const float*)d_in[2];
  const float* ow = (const float*)d_in[3];
  const float* ob = (const float*)d_in[4];
  char* ws = (char*)d_ws;
  unsigned short* xb = (unsigned short*)(ws + 0);        // 16 MB
  unsigned short* wv = (unsigned short*)(ws + 16777216); // 2 MB
  float* p    = (float*)(ws + 18874368);                 // 64 KB
  float* st   = (float*)(ws + 18939904);                 // 512 KB
  unsigned short* v = (unsigned short*)(ws + 19464192);  // 16 MB
  float* cmax = (float*)(ws + 36241408);                 // 16 KB
  float* csum = (float*)(ws + 36257792);                 // 16 KB
  float* cw   = (float*)(ws + 36274176);                 // 1 MB
  float* Mg   = (float*)(ws + 37322752);                 // 256 B
  float* E0   = (float*)(ws + 37323008);                 // 16 KB
  float* W0   = (float*)(ws + 37339392);                 // 1 MB
  float* h    = (float*)(ws + 38387968);                 // 2 MB
  float* out  = (float*)d_out;

  hipLaunchKernelGGL(prep_p,     dim3(64),     dim3(256),  0, stream, kv, q, p);
  hipLaunchKernelGGL(prep_wv,    dim3(16, 16), dim3(256),  0, stream, kv, wv);
  hipLaunchKernelGGL(stx_kernel, dim3(256),    dim3(256),  0, stream, x, p, xb, st);
  hipLaunchKernelGGL(vgemm,      dim3(8, 64),  dim3(256),  0, stream, xb, wv, v);
  hipLaunchKernelGGL(scan1,      dim3(4096),   dim3(64),   0, stream, st, v, cmax, csum, cw);
  hipLaunchKernelGGL(scan2,      dim3(64),     dim3(1024), 0, stream, cmax, csum, cw, Mg, E0, W0);
  hipLaunchKernelGGL(scan3,      dim3(64, 4),  dim3(1024), 0, stream, st, v, Mg, E0, W0, h);
  hipLaunchKernelGGL(fgemm,      dim3(8, 64),  dim3(256),  0, stream, h, ow, ob, out);
  // attribution probes — all writes go to dead-after-consumer buffers
  hipLaunchKernelGGL(probe_stx,   dim3(256),   dim3(256),  0, stream, x, p, xb, st);
  hipLaunchKernelGGL(probe_vgemm, dim3(8, 64), dim3(256),  0, stream, xb, wv, v);
  hipLaunchKernelGGL(probe_scan1, dim3(4096),  dim3(64),   0, stream, st, v, cmax, csum, cw);
  hipLaunchKernelGGL(probe_fgemm, dim3(8, 64), dim3(256),  0, stream, h, ow, ob, (float*)ws);
}

// Round 22
// 170.555 us; speedup vs baseline: 2.6841x; 2.6841x over previous
//
#include <hip/hip_runtime.h>
#include <stdint.h>

typedef __attribute__((ext_vector_type(4))) float f32x4;
typedef __attribute__((ext_vector_type(8))) short short8;

#define HEADS 16
#define TT 2048

__device__ __forceinline__ float b2f(unsigned short u) {
  return __builtin_bit_cast(float, (uint32_t)u << 16);
}
__device__ __forceinline__ unsigned short f2bf(float f) {
  uint32_t u = __builtin_bit_cast(uint32_t, f);
  u += 0x7fffu + ((u >> 16) & 1u);
  return (unsigned short)(u >> 16);
}
__device__ __forceinline__ uint32_t pk2(float a, float b) {
  return (uint32_t)f2bf(a) | ((uint32_t)f2bf(b) << 16);
}

// p[h][i] = sum_d Wk[i,h,d] * q[h,d]   (fold q into kv K-half; fp32)
__global__ void prep_p(const float* __restrict__ kv, const float* __restrict__ q,
                       float* __restrict__ p) {
  int idx = blockIdx.x * 256 + threadIdx.x;       // 16384 = 16*1024
  int h = idx >> 10, i = idx & 1023;
  const float* kvp = kv + (size_t)i * 2048 + (size_t)h * 128;
  const float* qp = q + h * 64;
  float s = 0.f;
#pragma unroll 8
  for (int d = 0; d < 64; ++d) s += kvp[2 * d] * qp[d];
  p[idx] = s;
}

// wv[hd][i] = bf16(kv[i*2048 + 2*hd + 1]) — LDS-tiled transpose
__global__ __launch_bounds__(256) void prep_wv(const float* __restrict__ kv,
                                               unsigned short* __restrict__ wv) {
  __shared__ unsigned short tile[64][66];
  int hd0 = blockIdx.x * 64, i0 = blockIdx.y * 64;
  int tid = threadIdx.x;
  int jj = tid & 63, r4 = tid >> 6;
#pragma unroll
  for (int s = 0; s < 16; ++s) {
    int ii = s * 4 + r4;
    tile[ii][jj] = f2bf(kv[(size_t)(i0 + ii) * 2048 + 2 * (hd0 + jj) + 1]);
  }
  __syncthreads();
#pragma unroll
  for (int s = 0; s < 16; ++s) {
    int jj2 = s * 4 + r4, ii2 = tid & 63;
    wv[(size_t)(hd0 + jj2) * 1024 + i0 + ii2] = tile[ii2][jj2];
  }
}

// stx v2 (r16: probe showed 27.5µs, 4.7M LDS bank conflicts from 4-scalar-
// store writes, 10.9% occupancy at 1 block/CU, 3 LDS reads+2 FMA per k).
// Now: 16-token blocks (grid 512 -> 2 blocks/CU), thread=(token,head) one
// head each, float4 LDS tiles pad-132 (16B-aligned rows -> b128 write/read,
// reads broadcast/2-way = free), 2.5x fewer issued instructions.
__global__ __launch_bounds__(256) void stx_kernel(const float* __restrict__ x,
                                                  const float* __restrict__ p,
                                                  unsigned short* __restrict__ xb,
                                                  float* __restrict__ st) {
  __shared__ float xs[16][132];                   // 132: rows 16B-aligned
  __shared__ float ps[16][132];
  int tid = threadIdx.x;
  int t0 = blockIdx.x * 16;
  int tt = tid & 15, hh = tid >> 4;               // token, head
  float a0 = 0.f;
  for (int kc = 0; kc < 1024; kc += 128) {
    __syncthreads();
#pragma unroll
    for (int vv = 0; vv < 2; ++vv) {              // x: 16 rows x 128 f32
      int idx = tid + vv * 256;
      int row = idx >> 5, c4 = idx & 31;
      float4 val = *(const float4*)&x[(size_t)(t0 + row) * 1024 + kc + c4 * 4];
      *(float4*)&xs[row][c4 * 4] = val;           // single b128 store
      *(uint2*)&xb[(size_t)(t0 + row) * 1024 + kc + c4 * 4] =
          uint2{pk2(val.x, val.y), pk2(val.z, val.w)};
    }
#pragma unroll
    for (int vv = 0; vv < 2; ++vv) {              // p: 16 rows x 128 f32
      int idx = tid + vv * 256;
      int row = idx >> 5, c4 = idx & 31;
      *(float4*)&ps[row][c4 * 4] =
          *(const float4*)&p[(size_t)row * 1024 + kc + c4 * 4];
    }
    __syncthreads();
#pragma unroll 8
    for (int kk = 0; kk < 128; kk += 4) {         // b128 reads, 4 FMA
      float4 xv = *(const float4*)&xs[tt][kk];
      float4 pv = *(const float4*)&ps[hh][kk];
      a0 += xv.x * pv.x + xv.y * pv.y + xv.z * pv.z + xv.w * pv.w;
    }
  }
  int tg = t0 + tt, b = tg >> 11, tl = tg & 2047;
  st[(size_t)(b * HEADS + hh) * TT + tl] = a0;
}

// V = xb @ Wv — MFMA 128x128 tile, K=1024, global_load_lds width=16 staging
__global__ __launch_bounds__(256) void vgemm(const unsigned short* __restrict__ A,
                                             const unsigned short* __restrict__ Bt,
                                             unsigned short* __restrict__ V) {
  __shared__ unsigned short As[128 * 32];         // 8 KB, linear
  __shared__ unsigned short Bs[128 * 32];         // 8 KB, linear
  int tid = threadIdx.x;
  int wave = tid >> 6, lane = tid & 63;
  int m0 = blockIdx.y * 128, n0 = blockIdx.x * 128;
  int wr = wave >> 1, wc = wave & 1;
  int lx = lane & 15, lq = lane >> 4;
  int srow = (wave << 4) + (lane >> 2);           // + c*64
  int scol = (lane & 3) << 3;
  unsigned short* AsW = As + (wave << 9);
  unsigned short* BsW = Bs + (wave << 9);
  f32x4 acc[4][4] = {};
  for (int kt = 0; kt < 1024; kt += 32) {
    __syncthreads();
#pragma unroll
    for (int c = 0; c < 2; ++c) {
      __builtin_amdgcn_global_load_lds(
          (const uint32_t*)&A[(size_t)(m0 + c * 64 + srow) * 1024 + kt + scol],
          (uint32_t*)(AsW + c * 2048), 16, 0, 0);
      __builtin_amdgcn_global_load_lds(
          (const uint32_t*)&Bt[(size_t)(n0 + c * 64 + srow) * 1024 + kt + scol],
          (uint32_t*)(BsW + c * 2048), 16, 0, 0);
    }
    __syncthreads();
    short8 af[4], bfr[4];
#pragma unroll
    for (int i = 0; i < 4; ++i)
      af[i] = *(const short8*)&As[(wr * 64 + i * 16 + lx) * 32 + lq * 8];
#pragma unroll
    for (int j = 0; j < 4; ++j)
      bfr[j] = *(const short8*)&Bs[(wc * 64 + j * 16 + lx) * 32 + lq * 8];
#pragma unroll
    for (int i = 0; i < 4; ++i)
#pragma unroll
      for (int j = 0; j < 4; ++j)
        acc[i][j] = __builtin_amdgcn_mfma_f32_16x16x32_bf16(af[i], bfr[j], acc[i][j], 0, 0, 0);
  }
#pragma unroll
  for (int i = 0; i < 4; ++i)
#pragma unroll
    for (int j = 0; j < 4; ++j)
#pragma unroll
      for (int r = 0; r < 4; ++r) {
        int m = m0 + wr * 64 + i * 16 + lq * 4 + r;
        int n = n0 + wc * 64 + j * 16 + lx;
        int b = m >> 11, tl = m & 2047, h = n >> 6, d = n & 63;
        V[((size_t)(b * HEADS + h) << 17) + (tl << 6) + d] = f2bf(acc[i][j][r]);
      }
}

// Phase 1: per-chunk (32 tok) max, exp-sum, weighted v-sums; loads hoisted
__global__ __launch_bounds__(64) void scan1(const float* __restrict__ st,
                                            const unsigned short* __restrict__ v,
                                            float* __restrict__ cmax,
                                            float* __restrict__ csum,
                                            float* __restrict__ cw) {
  int blk = blockIdx.x;                           // bh*64 + c
  int bh = blk >> 6, c = blk & 63;
  int lane = threadIdx.x;
  int t0 = c * 32;
  const float* stp = st + (size_t)bh * TT + t0;
  const unsigned short* vp = v + ((size_t)bh << 17) + ((size_t)t0 << 6);
  float vj[32];
#pragma unroll
  for (int j = 0; j < 32; ++j) vj[j] = b2f(vp[j * 64 + lane]);  // batched
  float stv = (lane < 32) ? stp[lane] : -1e30f;
  float Mc = stv;
#pragma unroll
  for (int off = 32; off; off >>= 1) Mc = fmaxf(Mc, __shfl_xor(Mc, off));
  float el = (lane < 32) ? __expf(stv - Mc) : 0.f;
  float S = el;
#pragma unroll
  for (int off = 32; off; off >>= 1) S += __shfl_xor(S, off);
  float W = 0.f;
#pragma unroll
  for (int j = 0; j < 32; ++j) W = fmaf(__shfl(el, j), vj[j], W);
  if (lane == 0) { cmax[blk] = Mc; csum[blk] = S; }
  cw[(size_t)blk * 64 + lane] = W;
}

// Phase 2: wave-parallel prefix over 64 chunks (lane = chunk). Exclusive via
// SHIFT of inclusive (subtraction-free — partial sums only involve chunks < c).
__global__ __launch_bounds__(1024) void scan2(const float* __restrict__ cmax,
                                              const float* __restrict__ csum,
                                              const float* __restrict__ cw,
                                              float* __restrict__ Mg,
                                              float* __restrict__ E0,
                                              float* __restrict__ W0) {
  int bh = blockIdx.x;
  int tid = threadIdx.x, wave = tid >> 6, lane = tid & 63;   // lane = chunk
  float cm = cmax[bh * 64 + lane];
  float M = cm;
#pragma unroll
  for (int off = 32; off; off >>= 1) M = fmaxf(M, __shfl_xor(M, off));
  float f = __expf(cm - M);
  if (wave == 0) {
    if (lane == 0) Mg[bh] = M;
    float incl = csum[bh * 64 + lane] * f;
#pragma unroll
    for (int off = 1; off < 64; off <<= 1) {
      float n = __shfl_up(incl, off);
      if (lane >= off) incl += n;
    }
    float excl = __shfl_up(incl, 1);              // shift, not subtract
    E0[bh * 64 + lane] = (lane == 0) ? 0.f : excl;
  }
#pragma unroll
  for (int dd = 0; dd < 4; ++dd) {
    int d = wave * 4 + dd;
    float incl = cw[((size_t)bh * 64 + lane) * 64 + d] * f;
#pragma unroll
    for (int off = 1; off < 64; off <<= 1) {
      float n = __shfl_up(incl, off);
      if (lane >= off) incl += n;
    }
    float excl = __shfl_up(incl, 1);              // shift, not subtract
    W0[((size_t)bh * 64 + lane) * 64 + d] = (lane == 0) ? 0.f : excl;
  }
}

// Phase 3: ATOMIC-FREE (r14: 48->~7µs confirmed).
__global__ __launch_bounds__(1024, 4) void scan3(const float* __restrict__ st,
                                                 const unsigned short* __restrict__ v,
                                                 const float* __restrict__ Mg,
                                                 const float* __restrict__ E0,
                                                 const float* __restrict__ W0,
                                                 float* __restrict__ h) {
  __shared__ float hq[16][16][64];                // 64 KB: [head][tok-half][dim]
  int tid = threadIdx.x;
  int wave = tid >> 6, lane = tid & 63;
  int c = blockIdx.x, b = blockIdx.y;
  int bh = b * HEADS + wave;
  int t0 = c * 32;
  const float* stp = st + (size_t)bh * TT + t0;
  const unsigned short* vp = v + ((size_t)bh << 17) + ((size_t)t0 << 6);
#define LOADV(J) float vj##J = b2f(vp[(J) * 64 + lane]);
  LOADV(0)  LOADV(1)  LOADV(2)  LOADV(3)  LOADV(4)  LOADV(5)  LOADV(6)  LOADV(7)
  LOADV(8)  LOADV(9)  LOADV(10) LOADV(11) LOADV(12) LOADV(13) LOADV(14) LOADV(15)
  LOADV(16) LOADV(17) LOADV(18) LOADV(19) LOADV(20) LOADV(21) LOADV(22) LOADV(23)
  LOADV(24) LOADV(25) LOADV(26) LOADV(27) LOADV(28) LOADV(29) LOADV(30) LOADV(31)
#undef LOADV
  float M = Mg[bh];
  float runU = E0[bh * 64 + c];
  float runW = W0[(size_t)(bh * 64 + c) * 64 + lane];
  float el = (lane < 32) ? __expf(stp[lane] - M) : 0.f;
#define STEP(J, JJ) { \
    float ej = __shfl(el, J); \
    runU += ej; \
    runW = fmaf(ej, vj##J, runW); \
    hq[wave][JJ][lane] = runW * __builtin_amdgcn_rcpf(fmaxf(runU, 1e-30f)) * 0.0625f; }
  STEP(0,0)   STEP(1,1)   STEP(2,2)   STEP(3,3)
  STEP(4,4)   STEP(5,5)   STEP(6,6)   STEP(7,7)
  STEP(8,8)   STEP(9,9)   STEP(10,10) STEP(11,11)
  STEP(12,12) STEP(13,13) STEP(14,14) STEP(15,15)
  __syncthreads();
  {                                               // wave = token, lane = dim
    float s = 0.f;
#pragma unroll
    for (int h2 = 0; h2 < 16; ++h2) s += hq[h2][wave][lane];
    h[((size_t)(b * TT + t0 + wave) << 6) + lane] = s;
  }
  __syncthreads();                                // hq reusable
  STEP(16,0)  STEP(17,1)  STEP(18,2)  STEP(19,3)
  STEP(20,4)  STEP(21,5)  STEP(22,6)  STEP(23,7)
  STEP(24,8)  STEP(25,9)  STEP(26,10) STEP(27,11)
  STEP(28,12) STEP(29,13) STEP(30,14) STEP(31,15)
#undef STEP
  __syncthreads();
  {
    float s = 0.f;
#pragma unroll
    for (int h2 = 0; h2 < 16; ++h2) s += hq[h2][wave][lane];
    h[((size_t)(b * TT + t0 + 16 + wave) << 6) + lane] = s;
  }
}

// out = h @ out_w^T + out_b  (fp32 -> bf16 staging; fp32 out, bias fused)
__global__ __launch_bounds__(256) void fgemm(const float* __restrict__ Ah,
                                             const float* __restrict__ Bw,
                                             const float* __restrict__ bias,
                                             float* __restrict__ C) {
  __shared__ unsigned short As[128 * 40];
  __shared__ unsigned short Bs[128 * 40];
  int tid = threadIdx.x;
  int wave = tid >> 6, lane = tid & 63;
  int m0 = blockIdx.y * 128, n0 = blockIdx.x * 128;
  int wr = wave >> 1, wc = wave & 1;
  int lx = lane & 15, lq = lane >> 4;
  f32x4 acc[4][4] = {};
  for (int kt = 0; kt < 64; kt += 32) {
    __syncthreads();
#pragma unroll
    for (int vv = 0; vv < 4; ++vv) {
      int c = tid + vv * 256;
      int r = (c & 511) >> 2, seg = c & 3;
      if (c < 512) {
        float4 a = *(const float4*)&Ah[(size_t)(m0 + r) * 64 + kt + seg * 8];
        float4 a2 = *(const float4*)&Ah[(size_t)(m0 + r) * 64 + kt + seg * 8 + 4];
        *(uint4*)&As[r * 40 + seg * 8] =
            uint4{pk2(a.x, a.y), pk2(a.z, a.w), pk2(a2.x, a2.y), pk2(a2.z, a2.w)};
      } else {
        float4 bq = *(const float4*)&Bw[(size_t)(n0 + r) * 64 + kt + seg * 8];
        float4 b2 = *(const float4*)&Bw[(size_t)(n0 + r) * 64 + kt + seg * 8 + 4];
        *(uint4*)&Bs[r * 40 + seg * 8] =
            uint4{pk2(bq.x, bq.y), pk2(bq.z, bq.w), pk2(b2.x, b2.y), pk2(b2.z, b2.w)};
      }
    }
    __syncthreads();
    short8 af[4], bfr[4];
#pragma unroll
    for (int i = 0; i < 4; ++i)
      af[i] = *(const short8*)&As[(wr * 64 + i * 16 + lx) * 40 + lq * 8];
#pragma unroll
    for (int j = 0; j < 4; ++j)
      bfr[j] = *(const short8*)&Bs[(wc * 64 + j * 16 + lx) * 40 + lq * 8];
#pragma unroll
    for (int i = 0; i < 4; ++i)
#pragma unroll
      for (int j = 0; j < 4; ++j)
        acc[i][j] = __builtin_amdgcn_mfma_f32_16x16x32_bf16(af[i], bfr[j], acc[i][j], 0, 0, 0);
  }
#pragma unroll
  for (int i = 0; i < 4; ++i)
#pragma unroll
    for (int j = 0; j < 4; ++j)
#pragma unroll
      for (int r = 0; r < 4; ++r) {
        int m = m0 + wr * 64 + i * 16 + lq * 4 + r;
        int n = n0 + wc * 64 + j * 16 + lx;
        C[(size_t)m * 1024 + n] = acc[i][j][r] + bias[n];
      }
}

extern "C" void kernel_launch(void* const* d_in, const int* in_sizes, int n_in,
                              void* d_out, int out_size, void* d_ws, size_t ws_size,
                              hipStream_t stream) {
  (void)in_sizes; (void)n_in; (void)out_size; (void)ws_size;
  const float* x  = (const float*)d_in[0];
  const float* kv = (const float*)d_in[1];
  const float* q  = (const float*)d_in[2];
  const float* ow = (const float*)d_in[3];
  const float* ob = (const float*)d_in[4];
  char* ws = (char*)d_ws;
  unsigned short* xb = (unsigned short*)(ws + 0);        // 16 MB
  unsigned short* wv = (unsigned short*)(ws + 16777216); // 2 MB
  float* p    = (float*)(ws + 18874368);                 // 64 KB
  float* st   = (float*)(ws + 18939904);                 // 512 KB
  unsigned short* v = (unsigned short*)(ws + 19464192);  // 16 MB
  float* cmax = (float*)(ws + 36241408);                 // 16 KB
  float* csum = (float*)(ws + 36257792);                 // 16 KB
  float* cw   = (float*)(ws + 36274176);                 // 1 MB
  float* Mg   = (float*)(ws + 37322752);                 // 256 B
  float* E0   = (float*)(ws + 37323008);                 // 16 KB
  float* W0   = (float*)(ws + 37339392);                 // 1 MB
  float* h    = (float*)(ws + 38387968);                 // 2 MB
  float* out  = (float*)d_out;

  hipLaunchKernelGGL(prep_p,     dim3(64),     dim3(256),  0, stream, kv, q, p);
  hipLaunchKernelGGL(prep_wv,    dim3(16, 16), dim3(256),  0, stream, kv, wv);
  hipLaunchKernelGGL(stx_kernel, dim3(512),    dim3(256),  0, stream, x, p, xb, st);
  hipLaunchKernelGGL(vgemm,      dim3(8, 64),  dim3(256),  0, stream, xb, wv, v);
  hipLaunchKernelGGL(scan1,      dim3(4096),   dim3(64),   0, stream, st, v, cmax, csum, cw);
  hipLaunchKernelGGL(scan2,      dim3(64),     dim3(1024), 0, stream, cmax, csum, cw, Mg, E0, W0);
  hipLaunchKernelGGL(scan3,      dim3(64, 4),  dim3(1024), 0, stream, st, v, Mg, E0, W0, h);
  hipLaunchKernelGGL(fgemm,      dim3(8, 64),  dim3(256),  0, stream, h, ow, ob, out);
}